// Round 3
// baseline (316.066 us; speedup 1.0000x reference)
//
#include <hip/hip_runtime.h>
#include <hip/hip_bf16.h>

typedef short bf16x8 __attribute__((ext_vector_type(8)));
typedef float f32x4 __attribute__((ext_vector_type(4)));

#define LOG2E 1.4426950408889634f
#define QKV_E ((size_t)24*4096*64)

__device__ __forceinline__ float bfu2f(unsigned short u) {
  unsigned v = ((unsigned)u) << 16;
  return __builtin_bit_cast(float, v);
}
__device__ __forceinline__ unsigned short f2bfu(float f) {
  unsigned u = __builtin_bit_cast(unsigned, f);
  u += 0x7fffu + ((u >> 16) & 1u);
  return (unsigned short)(u >> 16);
}
__device__ __forceinline__ float gelu_f(float v) {
  float a = fabsf(v) * 0.70710678118654752f;
  float t = 1.0f / (1.0f + 0.3275911f * a);
  float poly = ((((1.061405429f * t - 1.453152027f) * t + 1.421413741f) * t
                 - 0.284496736f) * t + 0.254829592f) * t;
  float erfa = 1.0f - poly * __expf(-a * a);
  float erfv = v >= 0.0f ? erfa : -erfa;
  return 0.5f * v * (1.0f + erfv);
}
__device__ __forceinline__ void gl_lds16(const ushort* g, ushort* l) {
  __builtin_amdgcn_global_load_lds(
      (const __attribute__((address_space(1))) unsigned int*)(const void*)g,
      (__attribute__((address_space(3))) unsigned int*)(void*)l, 16, 0, 0);
}

// ---------------- RMSNorm ----------------
__global__ __launch_bounds__(256) void rmsnorm_k(const float* __restrict__ x,
    const float* __restrict__ w, ushort* __restrict__ xn) {
  int row = blockIdx.x, t = threadIdx.x;
  const float* xr = x + (size_t)row * 768;
  float v0 = xr[t], v1 = xr[t + 256], v2 = xr[t + 512];
  float ss = v0 * v0 + v1 * v1 + v2 * v2;
#pragma unroll
  for (int m = 32; m >= 1; m >>= 1) ss += __shfl_xor(ss, m, 64);
  __shared__ float part[4];
  if ((t & 63) == 0) part[t >> 6] = ss;
  __syncthreads();
  float tot = part[0] + part[1] + part[2] + part[3];
  float rr = rsqrtf(tot * (1.0f / 768.0f) + 1e-6f);
  ushort* xo = xn + (size_t)row * 768;
  xo[t]       = f2bfu(v0 * rr * w[t]);
  xo[t + 256] = f2bfu(v1 * rr * w[t + 256]);
  xo[t + 512] = f2bfu(v2 * rr * w[t + 512]);
}

// ------------- transpose + fp32->bf16 -------------
__global__ __launch_bounds__(256) void tcvt_k(const float* __restrict__ in,
    ushort* __restrict__ out, int R, int C) {
  __shared__ float tile[32][33];
  int c0 = blockIdx.x * 32, r0 = blockIdx.y * 32;
  int t = threadIdx.x;
  int j = t & 31, i0 = t >> 5;
#pragma unroll
  for (int i = i0; i < 32; i += 8) tile[i][j] = in[(size_t)(r0 + i) * C + c0 + j];
  __syncthreads();
#pragma unroll
  for (int i = i0; i < 32; i += 8) out[(size_t)(c0 + i) * R + r0 + j] = f2bfu(tile[j][i]);
}

// ======== GEMM1: 256x256 tile, 8 waves, 4-phase/K-tile counted pipeline ====
// A [8192][768], Bt [5376][768] bf16. Fused bias+RoPE/scatter/vT/GELU epilogue.
// LDS: 2 bufs x (A 16384 + B 16384 ushorts) = 128KB.
// Stage: linear LDS dest, pre-swizzled global chunk (c ^ (row&7)).
__global__ __launch_bounds__(512, 2) void gemm1_k(const ushort* __restrict__ A,
    const ushort* __restrict__ Bt, const float* __restrict__ bias,
    const float* __restrict__ sn, const float* __restrict__ cs,
    ushort* __restrict__ qbuf, ushort* __restrict__ kbuf,
    ushort* __restrict__ vt, ushort* __restrict__ comb) {
  __shared__ __align__(16) ushort lds[65536];
  const int t = threadIdx.x, l = t & 63, w = t >> 6;
  const int wm = w >> 2, wn = w & 3;
  int bid = blockIdx.x;                     // 672 = 8 * 84
  int n = (bid & 7) * 84 + (bid >> 3);      // XCD-contiguous
  int bx = n >> 5, by = n & 31;             // col-major: B L2-resident per XCD
  const int mBase = by * 256, nBase = bx * 256;

  // per-thread staging offsets (4 rows-groups for A, same for B)
  size_t gA[4], gB[4];
  int ldst[4];
#pragma unroll
  for (int j = 0; j < 4; ++j) {
    int row = j * 64 + w * 8 + (l >> 3);
    int gc = ((l & 7) ^ (l >> 3)) * 8;
    gA[j] = (size_t)(mBase + row) * 768 + gc;
    gB[j] = (size_t)(nBase + row) * 768 + gc;
    ldst[j] = j * 4096 + w * 512;
  }

  f32x4 acc[8][4];
  f32x4 z = {0.f, 0.f, 0.f, 0.f};
#pragma unroll
  for (int mi = 0; mi < 8; ++mi)
#pragma unroll
    for (int nj = 0; nj < 4; ++nj) acc[mi][nj] = z;

  // prologue: stage tile 0 -> buf0
#pragma unroll
  for (int j = 0; j < 4; ++j) {
    gl_lds16(A + gA[j], lds + ldst[j]);
    gl_lds16(Bt + gB[j], lds + 16384 + ldst[j]);
  }
  asm volatile("s_waitcnt vmcnt(0)" ::: "memory");
  __builtin_amdgcn_s_barrier();

#pragma unroll 1
  for (int kt = 0; kt < 12; ++kt) {
    const int cur = kt & 1;
    const ushort* cA = lds + cur * 32768 + wm * 8192;
    const ushort* cB = lds + cur * 32768 + 16384 + (wn >> 1) * 8192;
#pragma unroll
    for (int q = 0; q < 4; ++q) {
      const int mq = q >> 1, nq = q & 1;
      if (q == 0 && kt + 1 < 12) {
        ushort* ob = lds + (1 - cur) * 32768;
        int k0 = (kt + 1) * 64;
#pragma unroll
        for (int j = 0; j < 4; ++j) {
          gl_lds16(A + gA[j] + k0, ob + ldst[j]);
          gl_lds16(Bt + gB[j] + k0, ob + 16384 + ldst[j]);
        }
      }
      bf16x8 af[4][2], bf[2][2];
#pragma unroll
      for (int mi = 0; mi < 4; ++mi) {
        int ri = mq * 64 + mi * 16 + (l & 15);
#pragma unroll
        for (int kk = 0; kk < 2; ++kk) {
          int slot = (kk * 4 + (l >> 4)) ^ (l & 7);
          af[mi][kk] = *(const bf16x8*)(cA + ri * 64 + slot * 8);
        }
      }
#pragma unroll
      for (int nj = 0; nj < 2; ++nj) {
        int ri = (wn & 1) * 64 + nq * 32 + nj * 16 + (l & 15);
#pragma unroll
        for (int kk = 0; kk < 2; ++kk) {
          int slot = (kk * 4 + (l >> 4)) ^ (l & 7);
          bf[nj][kk] = *(const bf16x8*)(cB + ri * 64 + slot * 8);
        }
      }
      if (q == 3) asm volatile("s_waitcnt vmcnt(0)" ::: "memory");
      __builtin_amdgcn_s_barrier();
      __builtin_amdgcn_s_setprio(1);
#pragma unroll
      for (int mi = 0; mi < 4; ++mi)
#pragma unroll
        for (int nj = 0; nj < 2; ++nj)
#pragma unroll
          for (int kk = 0; kk < 2; ++kk)
            acc[mq * 4 + mi][nq * 2 + nj] = __builtin_amdgcn_mfma_f32_16x16x32_bf16(
                bf[nj][kk], af[mi][kk], acc[mq * 4 + mi][nq * 2 + nj], 0, 0, 0);
      __builtin_amdgcn_s_setprio(0);
      __builtin_amdgcn_s_barrier();
    }
  }

  // epilogue: acc[mi][nj][r] -> (row = mBase+wm*128+mi*16+(l&15),
  //                              col = nBase+wn*64+nj*16+(l>>4)*4+r)
  const bool isff = (nBase >= 2304);
  const int region = nBase / 768;
#pragma unroll
  for (int mi = 0; mi < 8; ++mi) {
    int row = mBase + wm * 128 + mi * 16 + (l & 15);
    int b = row >> 12, s = row & 4095;
#pragma unroll
    for (int nj = 0; nj < 4; ++nj) {
      int col = nBase + wn * 64 + nj * 16 + ((l >> 4) << 2);
      f32x4 v = acc[mi][nj] + *(const f32x4*)(bias + col);
      if (isff) {
        ushort4 o;
        o.x = f2bfu(gelu_f(v[0]));
        o.y = f2bfu(gelu_f(v[1]));
        o.z = f2bfu(gelu_f(v[2]));
        o.w = f2bfu(gelu_f(v[3]));
        *(ushort4*)(comb + (size_t)row * 3840 + (col - 1536)) = o;
      } else {
        int rem = col - region * 768;
        int h = rem >> 6, d0 = rem & 63;
        if (region == 2) {
          size_t vb = (size_t)((b * 12 + h) * 64 + d0) * 4096 + s;
          vt[vb]          = f2bfu(v[0]);
          vt[vb + 4096]   = f2bfu(v[1]);
          vt[vb + 2*4096] = f2bfu(v[2]);
          vt[vb + 3*4096] = f2bfu(v[3]);
        } else {
          f32x4 sv = *(const f32x4*)(sn + (s << 6) + d0);
          f32x4 cv = *(const f32x4*)(cs + (s << 6) + d0);
          float o0 = v[0] * cv[0] - v[1] * sv[0];
          float o1 = v[1] * cv[0] + v[0] * sv[0];
          float o2 = v[2] * cv[2] - v[3] * sv[2];
          float o3 = v[3] * cv[2] + v[2] * sv[2];
          ushort4 o;
          if (region == 0) {
            o.x = f2bfu(o0 * 0.125f); o.y = f2bfu(o1 * 0.125f);
            o.z = f2bfu(o2 * 0.125f); o.w = f2bfu(o3 * 0.125f);
            *(ushort4*)(qbuf + ((size_t)((b * 12 + h) * 4096 + s)) * 64 + d0) = o;
          } else {
            o.x = f2bfu(o0); o.y = f2bfu(o1); o.z = f2bfu(o2); o.w = f2bfu(o3);
            *(ushort4*)(kbuf + ((size_t)((b * 12 + h) * 4096 + s)) * 64 + d0) = o;
          }
        }
      }
    }
  }
}

// ======== GEMM2: 128x128 split-K=2, double-buffered counted pipeline =======
__global__ __launch_bounds__(256) void gemm2_k(const ushort* __restrict__ Ain,
    const ushort* __restrict__ Btin, float* __restrict__ p0,
    float* __restrict__ p1) {
  __shared__ __align__(16) ushort lds[2][2][128 * 64];  // [buf][A/B]
  const int t = threadIdx.x, lane = t & 63, w = t >> 6;
  const int wr = w >> 1, wc = w & 1;
  int bid = blockIdx.x;                    // 768 = 8 * 96
  int n = (bid & 7) * 96 + (bid >> 3);
  int kz = n >= 384;
  int n2 = n - kz * 384;
  int by = n2 / 6, bx = n2 - by * 6;
  const int mBase = by * 128, nBase = bx * 128;
  const ushort* A = Ain + kz * 1920;
  const ushort* Bt = Btin + kz * 1920;

  size_t gA[4], gB[4];
  int ldst[4];
#pragma unroll
  for (int j = 0; j < 4; ++j) {
    int r = w * 32 + j * 8 + (lane >> 3);
    int gc = ((lane & 7) ^ ((lane >> 3) & 7)) * 8;
    gA[j] = (size_t)(mBase + r) * 3840 + gc;
    gB[j] = (size_t)(nBase + r) * 3840 + gc;
    ldst[j] = (w * 32 + j * 8) * 64;
  }

  f32x4 acc[4][4];
  f32x4 z = {0.f, 0.f, 0.f, 0.f};
#pragma unroll
  for (int m = 0; m < 4; ++m)
#pragma unroll
    for (int nn = 0; nn < 4; ++nn) acc[m][nn] = z;

#pragma unroll
  for (int j = 0; j < 4; ++j) {
    gl_lds16(A + gA[j], &lds[0][0][0] + ldst[j]);
    gl_lds16(Bt + gB[j], &lds[0][1][0] + ldst[j]);
  }
  asm volatile("s_waitcnt vmcnt(0)" ::: "memory");
  __builtin_amdgcn_s_barrier();

#pragma unroll 1
  for (int kt = 0; kt < 30; ++kt) {
    const int cur = kt & 1;
    if (kt + 1 < 30) {
      int k0 = (kt + 1) * 64;
#pragma unroll
      for (int j = 0; j < 4; ++j) {
        gl_lds16(A + gA[j] + k0, &lds[1 - cur][0][0] + ldst[j]);
        gl_lds16(Bt + gB[j] + k0, &lds[1 - cur][1][0] + ldst[j]);
      }
    }
    const ushort* As = &lds[cur][0][0];
    const ushort* Bs = &lds[cur][1][0];
#pragma unroll
    for (int kk = 0; kk < 2; ++kk) {
      bf16x8 af[4], bff[4];
#pragma unroll
      for (int m = 0; m < 4; ++m) {
        int row = wr * 64 + m * 16 + (lane & 15);
        int slot = (kk * 4 + (lane >> 4)) ^ (lane & 7);
        af[m] = *(const bf16x8*)(As + row * 64 + slot * 8);
      }
#pragma unroll
      for (int nn = 0; nn < 4; ++nn) {
        int row = wc * 64 + nn * 16 + (lane & 15);
        int slot = (kk * 4 + (lane >> 4)) ^ (lane & 7);
        bff[nn] = *(const bf16x8*)(Bs + row * 64 + slot * 8);
      }
      __builtin_amdgcn_s_setprio(1);
#pragma unroll
      for (int m = 0; m < 4; ++m)
#pragma unroll
        for (int nn = 0; nn < 4; ++nn)
          acc[m][nn] = __builtin_amdgcn_mfma_f32_16x16x32_bf16(bff[nn], af[m], acc[m][nn], 0, 0, 0);
      __builtin_amdgcn_s_setprio(0);
    }
    asm volatile("s_waitcnt vmcnt(0)" ::: "memory");
    __builtin_amdgcn_s_barrier();
  }

  float* p = kz ? p1 : p0;
#pragma unroll
  for (int m = 0; m < 4; ++m) {
    int row = mBase + wr * 64 + m * 16 + (lane & 15);
#pragma unroll
    for (int nn = 0; nn < 4; ++nn) {
      int col = nBase + wc * 64 + nn * 16 + ((lane >> 4) << 2);
      *(f32x4*)(p + (size_t)row * 768 + col) = acc[m][nn];
    }
  }
}

// -------- reduce: out = p0 + p1 + bias ------------------------------------
__global__ __launch_bounds__(256) void red_k(const float* __restrict__ p0,
    const float* __restrict__ p1, const float* __restrict__ bias,
    float* __restrict__ out) {
  const int n4 = 8192 * 768 / 4;
  for (int i = blockIdx.x * 256 + threadIdx.x; i < n4; i += gridDim.x * 256) {
    f32x4 a = *(const f32x4*)(p0 + 4 * (size_t)i);
    f32x4 b = *(const f32x4*)(p1 + 4 * (size_t)i);
    f32x4 c = *(const f32x4*)(bias + (4 * i) % 768);
    *(f32x4*)(out + 4 * (size_t)i) = a + b + c;
  }
}

// ---------------- windowed attention (flash-style, window 512) ------------
__global__ __launch_bounds__(256) void attn_k(const ushort* __restrict__ qb,
    const ushort* __restrict__ kb, const ushort* __restrict__ vt,
    ushort* __restrict__ comb) {
  __shared__ __align__(16) ushort Ks[128 * 64];
  __shared__ __align__(16) ushort Vs[64 * 128];
  __shared__ __align__(16) ushort Ps[4][32 * 128];
  int bid = blockIdx.x;                      // 768 blocks
  int nb = (bid & 7) * 96 + (bid >> 3);
  int qt = nb & 31, bh = nb >> 5;
  int t = threadIdx.x, lane = t & 63, w = t >> 6;
  int qlo = qt * 128;
  const size_t base = (size_t)bh * 4096 * 64;
  bf16x8 qa[2][2];
#pragma unroll
  for (int m = 0; m < 2; ++m)
#pragma unroll
    for (int kk = 0; kk < 2; ++kk) {
      int row = qlo + w * 32 + m * 16 + (lane & 15);
      qa[m][kk] = *(const bf16x8*)(qb + base + (size_t)row * 64 + kk * 32 + ((lane >> 4) << 3));
    }
  f32x4 z = {0.f, 0.f, 0.f, 0.f};
  f32x4 o[2][4];
  float m_run[2][4], l_run[2][4];
#pragma unroll
  for (int m = 0; m < 2; ++m)
#pragma unroll
    for (int r = 0; r < 4; ++r) { m_run[m][r] = -1e30f; l_run[m][r] = 0.f; }
#pragma unroll
  for (int m = 0; m < 2; ++m)
#pragma unroll
    for (int df = 0; df < 4; ++df) o[m][df] = z;
  ushort* pw = &Ps[w][0];
  int t0 = qt >= 4 ? qt - 4 : 0;
  for (int kt = t0; kt <= qt; ++kt) {
    int k0 = kt * 128;
    __syncthreads();
#pragma unroll
    for (int j = 0; j < 4; ++j) {
      int ch = t + 256 * j;
      int key = ch >> 3, c = ch & 7;
      *(int4*)(Ks + key * 64 + ((c ^ (key & 7)) << 3)) =
          *(const int4*)(kb + base + (size_t)(k0 + key) * 64 + c * 8);
      int dd = ch >> 4, c2 = ch & 15;
      *(int4*)(Vs + dd * 128 + ((c2 ^ (dd & 15)) << 3)) =
          *(const int4*)(vt + base + (size_t)dd * 4096 + k0 + c2 * 8);
    }
    __syncthreads();
    f32x4 s[2][8];
#pragma unroll
    for (int m = 0; m < 2; ++m)
#pragma unroll
      for (int nn = 0; nn < 8; ++nn) s[m][nn] = z;
#pragma unroll
    for (int kk = 0; kk < 2; ++kk) {
      bf16x8 kf[8];
#pragma unroll
      for (int nn = 0; nn < 8; ++nn) {
        int key = nn * 16 + (lane & 15);
        int c = kk * 4 + (lane >> 4);
        kf[nn] = *(const bf16x8*)(Ks + key * 64 + ((c ^ (key & 7)) << 3));
      }
#pragma unroll
      for (int m = 0; m < 2; ++m)
#pragma unroll
        for (int nn = 0; nn < 8; ++nn)
          s[m][nn] = __builtin_amdgcn_mfma_f32_16x16x32_bf16(qa[m][kk], kf[nn], s[m][nn], 0, 0, 0);
    }
#pragma unroll
    for (int m = 0; m < 2; ++m) {
#pragma unroll
      for (int r = 0; r < 4; ++r) {
        int qrow = qlo + w * 32 + m * 16 + ((lane >> 4) << 2) + r;
        float mx = -3e38f;
#pragma unroll
        for (int nn = 0; nn < 8; ++nn) {
          int krow = k0 + nn * 16 + (lane & 15);
          if ((unsigned)(qrow - krow) >= 512u) s[m][nn][r] = -3e38f;
          mx = fmaxf(mx, s[m][nn][r]);
        }
        mx = fmaxf(mx, __shfl_xor(mx, 1, 64));
        mx = fmaxf(mx, __shfl_xor(mx, 2, 64));
        mx = fmaxf(mx, __shfl_xor(mx, 4, 64));
        mx = fmaxf(mx, __shfl_xor(mx, 8, 64));
        float mo = m_run[m][r];
        float mn = fmaxf(mo, mx);
        float sc = exp2f((mo - mn) * LOG2E);
        m_run[m][r] = mn;
        l_run[m][r] *= sc;
#pragma unroll
        for (int df = 0; df < 4; ++df) o[m][df][r] *= sc;
        float ls = 0.f;
#pragma unroll
        for (int nn = 0; nn < 8; ++nn) {
          float p = exp2f((s[m][nn][r] - mn) * LOG2E);
          s[m][nn][r] = p;
          ls += p;
        }
        ls += __shfl_xor(ls, 1, 64);
        ls += __shfl_xor(ls, 2, 64);
        ls += __shfl_xor(ls, 4, 64);
        ls += __shfl_xor(ls, 8, 64);
        l_run[m][r] += ls;
      }
    }
#pragma unroll
    for (int m = 0; m < 2; ++m)
#pragma unroll
      for (int nn = 0; nn < 8; ++nn)
#pragma unroll
        for (int r = 0; r < 4; ++r) {
          int prow = m * 16 + ((lane >> 4) << 2) + r;
          int pcol = nn * 16 + (lane & 15);
          int c = pcol >> 3;
          pw[prow * 128 + ((c ^ (prow & 7)) << 3) + (pcol & 7)] = f2bfu(s[m][nn][r]);
        }
    __syncthreads();
#pragma unroll
    for (int kk2 = 0; kk2 < 4; ++kk2) {
      bf16x8 pa[2];
#pragma unroll
      for (int m = 0; m < 2; ++m) {
        int prow = m * 16 + (lane & 15);
        int c = kk2 * 4 + (lane >> 4);
        pa[m] = *(const bf16x8*)(pw + prow * 128 + ((c ^ (prow & 7)) << 3));
      }
#pragma unroll
      for (int df = 0; df < 4; ++df) {
        int dim = df * 16 + (lane & 15);
        int c = kk2 * 4 + (lane >> 4);
        bf16x8 vf = *(const bf16x8*)(Vs + dim * 128 + ((c ^ (dim & 15)) << 3));
#pragma unroll
        for (int m = 0; m < 2; ++m)
          o[m][df] = __builtin_amdgcn_mfma_f32_16x16x32_bf16(pa[m], vf, o[m][df], 0, 0, 0);
      }
    }
  }
  int b = bh / 12, h = bh - (bh / 12) * 12;
#pragma unroll
  for (int m = 0; m < 2; ++m)
#pragma unroll
    for (int df = 0; df < 4; ++df)
#pragma unroll
      for (int r = 0; r < 4; ++r) {
        int row = qlo + w * 32 + m * 16 + ((lane >> 4) << 2) + r;
        int dim = df * 16 + (lane & 15);
        float val = o[m][df][r] / l_run[m][r];
        comb[(size_t)(b * 4096 + row) * 3840 + h * 64 + dim] = f2bfu(val);
      }
}

extern "C" void kernel_launch(void* const* d_in, const int* in_sizes, int n_in,
                              void* d_out, int out_size, void* d_ws, size_t ws_size,
                              hipStream_t stream) {
  (void)in_sizes; (void)n_in; (void)out_size; (void)ws_size;
  const float* x      = (const float*)d_in[0];
  const float* sin_t  = (const float*)d_in[1];
  const float* cos_t  = (const float*)d_in[2];
  const float* w_norm = (const float*)d_in[3];
  const float* W_in   = (const float*)d_in[4];
  const float* b_in   = (const float*)d_in[5];
  const float* W_out  = (const float*)d_in[6];
  const float* b_out  = (const float*)d_in[7];
  float* out = (float*)d_out;

  const size_t XN_E  = (size_t)8192 * 768;
  ushort* xn      = (ushort*)d_ws;
  ushort* qbuf    = xn + XN_E;
  ushort* kbuf    = qbuf + QKV_E;
  ushort* vt      = kbuf + QKV_E;
  ushort* w_in_t  = vt + QKV_E;
  ushort* w_out_t = w_in_t + (size_t)5376 * 768;
  ushort* comb    = w_out_t + (size_t)768 * 3840;
  float* p0 = (float*)d_ws;                  // aliases xn/qbuf (dead by gemm2)
  float* p1 = p0 + (size_t)8192 * 768;       // aliases kbuf/vt

  rmsnorm_k<<<dim3(8192), dim3(256), 0, stream>>>(x, w_norm, xn);
  tcvt_k<<<dim3(5376 / 32, 768 / 32), dim3(256), 0, stream>>>(W_in, w_in_t, 768, 5376);
  tcvt_k<<<dim3(768 / 32, 3840 / 32), dim3(256), 0, stream>>>(W_out, w_out_t, 3840, 768);
  gemm1_k<<<dim3(672), dim3(512), 0, stream>>>(xn, w_in_t, b_in, sin_t, cos_t,
                                               qbuf, kbuf, vt, comb);
  attn_k<<<dim3(768), dim3(256), 0, stream>>>(qbuf, kbuf, vt, comb);
  gemm2_k<<<dim3(768), dim3(256), 0, stream>>>(comb, w_out_t, p0, p1);
  red_k<<<dim3(2048), dim3(256), 0, stream>>>(p0, p1, b_out, out);
}